// Round 13
// baseline (545.644 us; speedup 1.0000x reference)
//
#include <hip/hip_runtime.h>
#include <hip/hip_bf16.h>

// ParallelRetention pipeline, bf16 MFMA implementation.
// N=8192, all dims 1024 (Wp K=2048), groupnorm over (C,N) with 16 groups.
// Round 13: pkern2s -> pkern1p: single phase per K-tile (32 MFMA/barrier,
// 2-buffer 64KB LDS, vmcnt(0) drain masked by 2 blocks/CU), keeping R12's
// supertile XCD swizzle (FETCH 273MB) and the verified transpose epilogue.
// g1p GEMMs, fused cvt, gn unchanged.

typedef __bf16 bf16x8 __attribute__((ext_vector_type(8)));
typedef float f32x4 __attribute__((ext_vector_type(4)));
typedef unsigned short ushort_t;
typedef unsigned short ushort8 __attribute__((ext_vector_type(8)));

// ---------------------------------------------------------------- helpers

__device__ __forceinline__ void gload_lds16(const void* g, void* lds) {
  __builtin_amdgcn_global_load_lds((const __attribute__((address_space(1))) void*)g,
                                   (__attribute__((address_space(3))) void*)lds,
                                   16, 0, 0);
}

__device__ __forceinline__ ushort_t f2bu(float x) {
  __hip_bfloat16 h = __float2bfloat16(x);
  return *reinterpret_cast<ushort_t*>(&h);
}

#define FENCE() asm volatile("" ::: "memory")
#define BARRIER() do { FENCE(); __builtin_amdgcn_s_barrier(); FENCE(); } while (0)

// ---------------------------------------------------------------- f32 -> bf16 (all tensors, one launch)

struct CvtArgs {
  const float* src[8];
  __hip_bfloat16* dst[8];
  int base[8];   // first block of each segment; block = 1024 elems
};

__global__ void f2b_all(CvtArgs a) {
  const int b = blockIdx.x;
  int seg = 0;
#pragma unroll
  for (int s = 1; s < 8; ++s) seg = (b >= a.base[s]) ? s : seg;
  const int i4 = (b - a.base[seg]) * 1024 + threadIdx.x * 4;
  const float4 v = *(const float4*)(a.src[seg] + i4);
  ushort4 o;
  o.x = f2bu(v.x); o.y = f2bu(v.y); o.z = f2bu(v.z); o.w = f2bu(v.w);
  *(ushort4*)((ushort_t*)a.dst[seg] + i4) = o;
}

// ---------------------------------------------------------------- g1p: generic GEMM C = A*B^T
// 128x256 tile, BK=64, 512 threads = 8 waves (2m x 4n). ONE phase per K-tile:
// {16 ds_read_b128, stage t+2 (6 gloads) -> buf (t+2)%3, lgkmcnt(0), 32 MFMA,
//  vmcnt(6) gate, barrier}. 3 LDS buffers x 48 KB = 144 KB, 1 block/CU.
// EPI: 0=+biasN; 1=+biasM; 2=plain; 3=rowsum-scale+biasN+GELU; 4=+biasN+PReLU,f32,gstats
template <int EPI>
__global__ __launch_bounds__(512, 2)
void g1p(const __hip_bfloat16* __restrict__ A, const __hip_bfloat16* __restrict__ B,
         __hip_bfloat16* __restrict__ Cb, float* __restrict__ Cf,
         int K, int ldc, int nbnLog2,
         const float* __restrict__ biasN, const float* __restrict__ biasM,
         const float* __restrict__ rowsum, const float* __restrict__ prelu_w,
         float* __restrict__ gstats) {
  __shared__ __align__(16) char ldsm[147456];  // 3 x (A 16KB + B 32KB)
  const int tid = threadIdx.x, w = tid >> 6, l = tid & 63;
  const int wm = w >> 2, wn = w & 3;

  // XCD chunk swizzle (grid 256, chunk 32/XCD)
  const int orig = blockIdx.x;
  const int wg = (orig & 7) * 32 + (orig >> 3);
  const int bm = wg >> nbnLog2, bn = wg & ((1 << nbnLog2) - 1);

  const size_t rowB = (size_t)K * 2;
  const char* Ag = (const char*)A + (size_t)bm * 128 * rowB;
  const char* Bg = (const char*)B + (size_t)bn * 256 * rowB;
  const int NT = K >> 6;

  // Stage one 128x64 unit (16 KB, 1024 chunks); 512 thr -> 2 gloads each.
  auto stageU = [&](char* ldsu, const char* srcbase) {
#pragma unroll
    for (int i = 0; i < 2; ++i) {
      const int cb = i * 512 + w * 64;
      const int c = cb + l;
      const int r = c >> 3;
      const int j = (c & 7) ^ (r & 7);
      gload_lds16(srcbase + (size_t)r * rowB + j * 16, ldsu + cb * 16);
    }
  };
  // Stage full K-tile (A + B lo + B hi) = 6 gloads/thread
  auto stT = [&](char* buf, int kt) {
    stageU(buf, Ag + (size_t)kt * 128);
    stageU(buf + 16384, Bg + (size_t)kt * 128);
    stageU(buf + 32768, Bg + (size_t)128 * rowB + (size_t)kt * 128);
  };

  auto rdA = [&](const char* buf, int f, int kk) -> bf16x8 {
    const int R = wm * 64 + f * 16 + (l & 15);
    const int j = kk * 4 + (l >> 4);
    const int chunk = R * 8 + (j ^ (R & 7));
    return *(const bf16x8*)(buf + chunk * 16);
  };
  auto rdB = [&](const char* buf, int nf, int kk) -> bf16x8 {
    const int Rg = wn * 64 + nf * 16 + (l & 15);
    const int hh = Rg >> 7, Rl = Rg & 127;
    const int j = kk * 4 + (l >> 4);
    const int chunk = Rl * 8 + (j ^ (Rl & 7));
    return *(const bf16x8*)(buf + 16384 + hh * 16384 + chunk * 16);
  };

  char* pa = ldsm;
  char* pb = ldsm + 49152;
  char* pc = ldsm + 98304;

  // Prologue: tile0 -> pa, tile1 -> pb (12 loads); drain tile0 (vmcnt(6)).
  stT(pa, 0); stT(pb, 1);
  asm volatile("s_waitcnt vmcnt(6)" ::: "memory");
  BARRIER();

  f32x4 acc[4][4] = {};
  bf16x8 Af[4][2], Bf[4][2];

#pragma unroll 1
  for (int t = 0; t < NT; ++t) {
    const bool s1 = (t + 1 < NT), s2 = (t + 2 < NT);
    // reads of tile t (16 x ds_read_b128)
#pragma unroll
    for (int f = 0; f < 4; ++f)
#pragma unroll
      for (int kk = 0; kk < 2; ++kk) Af[f][kk] = rdA(pa, f, kk);
#pragma unroll
    for (int nf = 0; nf < 4; ++nf)
#pragma unroll
      for (int kk = 0; kk < 2; ++kk) Bf[nf][kk] = rdB(pa, nf, kk);
    // stage tile t+2 into pc (its last reads finished in iter t-1, barrier'd)
    if (s2) stT(pc, t + 2);
    asm volatile("s_waitcnt lgkmcnt(0)" ::: "memory");
    __builtin_amdgcn_sched_barrier(0);
    // 32 MFMA, kk outermost
    __builtin_amdgcn_s_setprio(1);
#pragma unroll
    for (int kk = 0; kk < 2; ++kk)
#pragma unroll
      for (int f = 0; f < 4; ++f)
#pragma unroll
        for (int g = 0; g < 4; ++g)
          acc[f][g] = __builtin_amdgcn_mfma_f32_16x16x32_bf16(Af[f][kk], Bf[g][kk], acc[f][g], 0, 0, 0);
    __builtin_amdgcn_s_setprio(0);
    // gate: tile t+1 resident (drains its 6; leaves t+2's 6 in flight)
    if (s2)      asm volatile("s_waitcnt vmcnt(6)" ::: "memory");
    else if (s1) asm volatile("s_waitcnt vmcnt(0)" ::: "memory");
    BARRIER();
    char* tmp = pa; pa = pb; pb = pc; pc = tmp;
  }

  // Epilogue
  const int r0 = bm * 128 + wm * 64, c0 = bn * 256 + wn * 64;
  float gs = 0.f, gq = 0.f;
#pragma unroll
  for (int mf = 0; mf < 4; ++mf) {
#pragma unroll
    for (int i = 0; i < 4; ++i) {
      const int row = r0 + mf * 16 + ((l >> 4) << 2) + i;
      float rscale = 1.0f;
      if (EPI == 3) rscale = 1.0f / rowsum[row];
#pragma unroll
      for (int nf = 0; nf < 4; ++nf) {
        const int col = c0 + nf * 16 + (l & 15);
        float v = acc[mf][nf][i];
        if (EPI == 0) {
          v += biasN[col];
        } else if (EPI == 1) {
          v += biasM[row];
        } else if (EPI == 3) {
          v = v * rscale + biasN[col];
          v = 0.5f * v * (1.0f + erff(v * 0.70710678118654752f));
        } else if (EPI == 4) {
          v += biasN[col];
          v = (v >= 0.f) ? v : prelu_w[col] * v;
        }
        if (EPI == 4) {
          Cf[(size_t)row * ldc + col] = v;
          gs += v; gq += v * v;
        } else {
          Cb[(size_t)row * ldc + col] = __float2bfloat16(v);
        }
      }
    }
  }
  if (EPI == 4) {
#pragma unroll
    for (int m = 1; m < 64; m <<= 1) {
      gs += __shfl_xor(gs, m);
      gq += __shfl_xor(gq, m);
    }
    if (l == 0) {
      const int g = c0 >> 6;
      atomicAdd(&gstats[g * 2 + 0], gs);
      atomicAdd(&gstats[g * 2 + 1], gq);
    }
  }
}

// ---------------------------------------------------------------- pkern1p
// P = exp(D .* (Q K^T) / 32) + per-row sums.  128x128 tile, BK=64, 256 thr,
// 4 waves (2x2 of 64x64). ONE phase per K-tile: {16 ds_read_b128, stage t+1
// -> buf^1 (8 gloads), lgkmcnt(0), 32 MFMA, vmcnt(0), barrier}. 2 buffers x
// 32 KB = 64 KB -> 2 blocks/CU; the co-resident block masks the vmcnt(0)
// drain (pkern2s premise) while barrier count drops 4x per K-tile.
// Supertile XCD swizzle (R12: FETCH 273 MB). Epilogue: LDS transpose
// (EPAD2 132, 64-row halves) + T14 D-prefetch.
#define EPAD2 132
__global__ __launch_bounds__(256, 2)
void pkern1p(const __hip_bfloat16* __restrict__ Q, const __hip_bfloat16* __restrict__ Kmat,
             const float* __restrict__ D, __hip_bfloat16* __restrict__ P,
             float* __restrict__ rowsum, int nt) {
  __shared__ __align__(16) char ldsm[65536];  // 2 bufs x (A 16KB + B 16KB); epi 64*132*4=33.8KB
  const int tid = threadIdx.x, w = tid >> 6, l = tid & 63;
  const int wm = w >> 1, wn = w & 1;

  // Supertile swizzle (grid 4096 = 64x64 blocks; stile 8x8; XCD x = stile-col x)
  const int orig = blockIdx.x;
  const int x = orig & 7;          // XCD
  const int i = orig >> 3;         // 0..511 within XCD
  const int sr = i >> 6;           // stile row 0..7
  const int p = i & 63;            // pos in stile
  const int bm = sr * 8 + (p >> 3);
  const int bn = x * 8 + (p & 7);

  const char* Ag = (const char*)Q + (size_t)bm * 128 * 2048;
  const char* Bg = (const char*)Kmat + (size_t)bn * 128 * 2048;

  // Stage one 128-row x 64-col unit (16 KB = 1024 chunks); 256 thr -> 4 gloads.
  auto stageU = [&](int pbuf, int unit, const char* srcbase) {
    char* ldsu = ldsm + pbuf * 32768 + unit * 16384;
#pragma unroll
    for (int q = 0; q < 4; ++q) {
      const int cb = q * 256 + w * 64;
      const int c = cb + l;
      const int r = c >> 3;
      const int j = (c & 7) ^ (r & 7);
      gload_lds16(srcbase + (size_t)r * 2048 + j * 16, ldsu + cb * 16);
    }
  };
  auto stT = [&](int pbuf, int kt) {
    stageU(pbuf, 0, Ag + (size_t)kt * 128);
    stageU(pbuf, 1, Bg + (size_t)kt * 128);
  };

  auto rdA = [&](int pbuf, int f, int kk) -> bf16x8 {
    const int R = wm * 64 + f * 16 + (l & 15);
    const int j = kk * 4 + (l >> 4);
    const int chunk = R * 8 + (j ^ (R & 7));
    return *(const bf16x8*)(ldsm + pbuf * 32768 + chunk * 16);
  };
  auto rdB = [&](int pbuf, int nf, int kk) -> bf16x8 {
    const int R = wn * 64 + nf * 16 + (l & 15);
    const int j = kk * 4 + (l >> 4);
    const int chunk = R * 8 + (j ^ (R & 7));
    return *(const bf16x8*)(ldsm + pbuf * 32768 + 16384 + chunk * 16);
  };

  // Prologue: tile0 -> buf0 (8 gloads), drain.
  stT(0, 0);
  asm volatile("s_waitcnt vmcnt(0)" ::: "memory");
  BARRIER();

  f32x4 acc[4][4] = {};
  bf16x8 Af[4][2], Bf[4][2];

#pragma unroll 1
  for (int t = 0; t < nt; ++t) {
    const int pbuf = t & 1;
    const bool s1 = (t + 1 < nt);
    // reads of tile t (16 x ds_read_b128)
#pragma unroll
    for (int f = 0; f < 4; ++f)
#pragma unroll
      for (int kk = 0; kk < 2; ++kk) Af[f][kk] = rdA(pbuf, f, kk);
#pragma unroll
    for (int nf = 0; nf < 4; ++nf)
#pragma unroll
      for (int kk = 0; kk < 2; ++kk) Bf[nf][kk] = rdB(pbuf, nf, kk);
    // stage tile t+1 into the other buffer (its reads finished last iter)
    if (s1) stT(pbuf ^ 1, t + 1);
    asm volatile("s_waitcnt lgkmcnt(0)" ::: "memory");
    __builtin_amdgcn_sched_barrier(0);
    // 32 MFMA, kk outermost
    __builtin_amdgcn_s_setprio(1);
#pragma unroll
    for (int kk = 0; kk < 2; ++kk)
#pragma unroll
      for (int f = 0; f < 4; ++f)
#pragma unroll
        for (int g = 0; g < 4; ++g)
          acc[f][g] = __builtin_amdgcn_mfma_f32_16x16x32_bf16(Af[f][kk], Bf[g][kk], acc[f][g], 0, 0, 0);
    __builtin_amdgcn_s_setprio(0);
    // drain tile t+1's stage (masked by the co-resident block on this CU)
    if (s1) asm volatile("s_waitcnt vmcnt(0)" ::: "memory");
    BARRIER();
  }

  // ---- Epilogue: LDS transpose in 64-row halves + T14 D-prefetch ----
  float* lds32 = (float*)ldsm;
  const int rbase = bm * 128, cbase = bn * 128;
  const int rth = tid >> 3;            // 0..31 row within 32-row chunk
  const int cl = (tid & 7) * 16;       // 0..112
#pragma unroll 1
  for (int h = 0; h < 2; ++h) {
    // (1) prefetch this half's D (rows h*64 + it*32 + rth), 8 float4 = 32 VGPR
    float4 dreg[8];
#pragma unroll
    for (int it = 0; it < 2; ++it) {
      const size_t gof = (size_t)(rbase + h * 64 + it * 32 + rth) * 8192 + (cbase + cl);
#pragma unroll
      for (int q = 0; q < 4; ++q) dreg[it * 4 + q] = *(const float4*)(D + gof + q * 4);
    }
    // (2) dump half h's acc (waves wm==h) into LDS [64][EPAD2]
    BARRIER();
    if (wm == h) {
#pragma unroll
      for (int mf = 0; mf < 4; ++mf)
#pragma unroll
        for (int nf = 0; nf < 4; ++nf)
#pragma unroll
          for (int i2 = 0; i2 < 4; ++i2)
            lds32[(mf * 16 + ((l >> 4) << 2) + i2) * EPAD2 + (wn * 64 + nf * 16 + (l & 15))] =
                acc[mf][nf][i2];
    }
    asm volatile("s_waitcnt lgkmcnt(0)" ::: "memory");
    BARRIER();
    // (3) consume: 2 iters x 32 rows; 8 thr/row x 16 f32
#pragma unroll
    for (int it = 0; it < 2; ++it) {
      const int rl = it * 32 + rth;
      const int row = rbase + h * 64 + rl;
      const size_t gof = (size_t)row * 8192 + (cbase + cl);
      float pv[16];
#pragma unroll
      for (int q = 0; q < 4; ++q) {
        const float4 s = *(const float4*)(lds32 + rl * EPAD2 + cl + q * 4);
        const float4 d = dreg[it * 4 + q];
        pv[q * 4 + 0] = __expf(d.x * (s.x * 0.03125f));
        pv[q * 4 + 1] = __expf(d.y * (s.y * 0.03125f));
        pv[q * 4 + 2] = __expf(d.z * (s.z * 0.03125f));
        pv[q * 4 + 3] = __expf(d.w * (s.w * 0.03125f));
      }
      ushort8 o0, o1;
#pragma unroll
      for (int q = 0; q < 8; ++q) { o0[q] = f2bu(pv[q]); o1[q] = f2bu(pv[8 + q]); }
      *(ushort8*)((ushort_t*)P + gof) = o0;
      *(ushort8*)((ushort_t*)P + gof + 8) = o1;
      float rs = 0.f;
#pragma unroll
      for (int q = 0; q < 16; ++q) rs += pv[q];
      rs += __shfl_xor(rs, 1); rs += __shfl_xor(rs, 2); rs += __shfl_xor(rs, 4);
      if ((tid & 7) == 0) atomicAdd(&rowsum[row], rs);
    }
  }
}
#undef EPAD2

// ---------------------------------------------------------------- GroupNorm finalize

__global__ void gn_finalize(const float* __restrict__ x, const float* __restrict__ gstats,
                            const float* __restrict__ gw, const float* __restrict__ gb,
                            float* __restrict__ out, int n) {
  __shared__ float sm[16], sr[16];
  if (threadIdx.x < 16) {
    const float cnt = 64.0f * 8192.0f;
    const float s = gstats[threadIdx.x * 2 + 0];
    const float q = gstats[threadIdx.x * 2 + 1];
    const float mean = s / cnt;
    const float var = q / cnt - mean * mean;
    sm[threadIdx.x] = mean;
    sr[threadIdx.x] = rsqrtf(var + 1e-5f);
  }
  __syncthreads();
  const int i4 = (blockIdx.x * 256 + threadIdx.x) * 4;
  if (i4 >= n) return;
  const float4 v = *(const float4*)(x + i4);
  const int c = i4 & 1023;
  const int g = c >> 6;
  const float mean = sm[g], r = sr[g];
  float4 o;
  o.x = (v.x - mean) * r * gw[c + 0] + gb[c + 0];
  o.y = (v.y - mean) * r * gw[c + 1] + gb[c + 1];
  o.z = (v.z - mean) * r * gw[c + 2] + gb[c + 2];
  o.w = (v.w - mean) * r * gw[c + 3] + gb[c + 3];
  *(float4*)(out + i4) = o;
}

// ---------------------------------------------------------------- launch

extern "C" void kernel_launch(void* const* d_in, const int* in_sizes, int n_in,
                              void* d_out, int out_size, void* d_ws, size_t ws_size,
                              hipStream_t stream) {
  const float* h  = (const float*)d_in[0];
  const float* D  = (const float*)d_in[1];
  const float* hp = (const float*)d_in[2];
  const float* Wq = (const float*)d_in[3];
  const float* bq = (const float*)d_in[4];
  const float* Wk = (const float*)d_in[5];
  const float* bk = (const float*)d_in[6];
  const float* Wv = (const float*)d_in[7];
  const float* bv = (const float*)d_in[8];
  const float* Wr = (const float*)d_in[9];
  const float* br = (const float*)d_in[10];
  const float* Wc = (const float*)d_in[11];
  const float* bc = (const float*)d_in[12];
  const float* Wp = (const float*)d_in[13];
  const float* bp = (const float*)d_in[14];
  const float* pw = (const float*)d_in[15];
  const float* gw = (const float*)d_in[16];
  const float* gb = (const float*)d_in[17];
  float* out = (float*)d_out;

  char* ws = (char*)d_ws;
  size_t off = 0;
  auto alloc = [&](size_t b) {
    char* p = ws + off;
    off += (b + 255) & ~(size_t)255;
    return p;
  };
  __hip_bfloat16* hb   = (__hip_bfloat16*)alloc(8192ull * 1024 * 2);
  __hip_bfloat16* hpb  = (__hip_bfloat16*)alloc(8192ull * 1024 * 2);
  __hip_bfloat16* Wqb  = (__hip_bfloat16*)alloc(1024ull * 1024 * 2);
  __hip_bfloat16* Wkb  = (__hip_bfloat16*)alloc(1024ull * 1024 * 2);
  __hip_bfloat16* Wvb  = (__hip_bfloat16*)alloc(1024ull * 1024 * 2);
  __hip_bfloat16* Wrb  = (__hip_bfloat16*)alloc(1024ull * 1024 * 2);
  __hip_bfloat16* Wcb  = (__hip_bfloat16*)alloc(1024ull * 1024 * 2);
  __hip_bfloat16* Wpb  = (__hip_bfloat16*)alloc(1024ull * 2048 * 2);
  __hip_bfloat16* Qb   = (__hip_bfloat16*)alloc(8192ull * 1024 * 2);
  __hip_bfloat16* Kb   = (__hip_bfloat16*)alloc(8192ull * 1024 * 2);
  __hip_bfloat16* Vt   = (__hip_bfloat16*)alloc(1024ull * 8192 * 2);
  __hip_bfloat16* R0   = (__hip_bfloat16*)alloc(8192ull * 1024 * 2);
  __hip_bfloat16* comb = (__hip_bfloat16*)alloc(8192ull * 2048 * 2);
  __hip_bfloat16* P    = (__hip_bfloat16*)alloc(8192ull * 8192 * 2);
  float* xbuf   = (float*)alloc(8192ull * 1024 * 4);
  float* rowsum = (float*)alloc(8192ull * 4);
  float* gstats = (float*)alloc(128);
  if (off > ws_size) return;

  hipMemsetAsync(rowsum, 0, 8192 * 4, stream);
  hipMemsetAsync(gstats, 0, 128, stream);

  // All conversions in one launch. Segments (blocks of 1024 elems):
  CvtArgs ca;
  ca.src[0] = h;  ca.dst[0] = hb;  ca.base[0] = 0;
  ca.src[1] = hp; ca.dst[1] = hpb; ca.base[1] = 8192;
  ca.src[2] = Wq; ca.dst[2] = Wqb; ca.base[2] = 16384;
  ca.src[3] = Wk; ca.dst[3] = Wkb; ca.base[3] = 17408;
  ca.src[4] = Wv; ca.dst[4] = Wvb; ca.base[4] = 18432;
  ca.src[5] = Wr; ca.dst[5] = Wrb; ca.base[5] = 19456;
  ca.src[6] = Wc; ca.dst[6] = Wcb; ca.base[6] = 20480;
  ca.src[7] = Wp; ca.dst[7] = Wpb; ca.base[7] = 21504;
  f2b_all<<<dim3(23552), 256, 0, stream>>>(ca);

  // Q = h Wq^T + bq ; K = h Wk^T + bk     [8192,1024]
  g1p<0><<<dim3(256), 512, 0, stream>>>(hb, Wqb, Qb, nullptr, 1024, 1024, 2, bq, nullptr, nullptr, nullptr, nullptr);
  g1p<0><<<dim3(256), 512, 0, stream>>>(hb, Wkb, Kb, nullptr, 1024, 1024, 2, bk, nullptr, nullptr, nullptr, nullptr);
  // Vt = Wv h^T + bv(per row)             [1024,8192]
  g1p<1><<<dim3(256), 512, 0, stream>>>(Wvb, hb, Vt, nullptr, 1024, 8192, 5, nullptr, bv, nullptr, nullptr, nullptr);
  // P = exp(D .* QK^T/32), rowsum         [8192,8192]  (single-phase 2-blk/CU engine)
  pkern1p<<<dim3(4096), 256, 0, stream>>>(Qb, Kb, D, P, rowsum, 16);
  // R0 = P V (= P Vt^T)                   [8192,1024]
  g1p<2><<<dim3(256), 512, 0, stream>>>(P, Vt, R0, nullptr, 8192, 1024, 2, nullptr, nullptr, nullptr, nullptr, nullptr);
  // comb[:, :1024] = gelu((R0 Wr^T)/rowsum + br)
  g1p<3><<<dim3(256), 512, 0, stream>>>(R0, Wrb, comb, nullptr, 1024, 2048, 2, br, nullptr, rowsum, nullptr, nullptr);
  // comb[:, 1024:] = hp Wc^T + bc
  g1p<0><<<dim3(256), 512, 0, stream>>>(hpb, Wcb, comb + 1024, nullptr, 1024, 2048, 2, bc, nullptr, nullptr, nullptr, nullptr);
  // x = prelu(comb Wp^T + bp), group stats
  g1p<4><<<dim3(256), 512, 0, stream>>>(comb, Wpb, nullptr, xbuf, 2048, 1024, 2, bp, nullptr, nullptr, pw, gstats);
  // groupnorm
  gn_finalize<<<dim3(8192), 256, 0, stream>>>(xbuf, gstats, gw, gb, out, 8192 * 1024);
}

// Round 14
// 531.623 us; speedup vs baseline: 1.0264x; 1.0264x over previous
//
#include <hip/hip_runtime.h>
#include <hip/hip_bf16.h>

// ParallelRetention pipeline, bf16 MFMA implementation.
// N=8192, all dims 1024 (Wp K=2048), groupnorm over (C,N) with 16 groups.
// Round 14: revert pkern to R12's pkern2s (R13's 1-phase/vmcnt(0) regressed:
// counted-gate needs 3 bufs = 96KB = 1 blk/CU, losing epilogue overlap).
// Micro-opt: xbuf f32->bf16 (Wp GEMM writes bf16, gn reads ushort8; stats
// stay f32) — saves ~32 MB traffic.

typedef __bf16 bf16x8 __attribute__((ext_vector_type(8)));
typedef float f32x4 __attribute__((ext_vector_type(4)));
typedef unsigned short ushort_t;
typedef unsigned short ushort8 __attribute__((ext_vector_type(8)));

// ---------------------------------------------------------------- helpers

__device__ __forceinline__ void gload_lds16(const void* g, void* lds) {
  __builtin_amdgcn_global_load_lds((const __attribute__((address_space(1))) void*)g,
                                   (__attribute__((address_space(3))) void*)lds,
                                   16, 0, 0);
}

__device__ __forceinline__ ushort_t f2bu(float x) {
  __hip_bfloat16 h = __float2bfloat16(x);
  return *reinterpret_cast<ushort_t*>(&h);
}

__device__ __forceinline__ float bu2f(ushort_t u) {
  __hip_bfloat16 h = *reinterpret_cast<__hip_bfloat16*>(&u);
  return __bfloat162float(h);
}

#define FENCE() asm volatile("" ::: "memory")
#define BARRIER() do { FENCE(); __builtin_amdgcn_s_barrier(); FENCE(); } while (0)

// ---------------------------------------------------------------- f32 -> bf16 (all tensors, one launch)

struct CvtArgs {
  const float* src[8];
  __hip_bfloat16* dst[8];
  int base[8];   // first block of each segment; block = 1024 elems
};

__global__ void f2b_all(CvtArgs a) {
  const int b = blockIdx.x;
  int seg = 0;
#pragma unroll
  for (int s = 1; s < 8; ++s) seg = (b >= a.base[s]) ? s : seg;
  const int i4 = (b - a.base[seg]) * 1024 + threadIdx.x * 4;
  const float4 v = *(const float4*)(a.src[seg] + i4);
  ushort4 o;
  o.x = f2bu(v.x); o.y = f2bu(v.y); o.z = f2bu(v.z); o.w = f2bu(v.w);
  *(ushort4*)((ushort_t*)a.dst[seg] + i4) = o;
}

// ---------------------------------------------------------------- g1p: generic GEMM C = A*B^T
// 128x256 tile, BK=64, 512 threads = 8 waves (2m x 4n). ONE phase per K-tile:
// {16 ds_read_b128, stage t+2 (6 gloads) -> buf (t+2)%3, lgkmcnt(0), 32 MFMA,
//  vmcnt(6) gate, barrier}. 3 LDS buffers x 48 KB = 144 KB, 1 block/CU.
// EPI: 0=+biasN; 1=+biasM; 2=plain; 3=rowsum-scale+biasN+GELU;
//      4=+biasN+PReLU, bf16 out + group sum/sumsq atomics
template <int EPI>
__global__ __launch_bounds__(512, 2)
void g1p(const __hip_bfloat16* __restrict__ A, const __hip_bfloat16* __restrict__ B,
         __hip_bfloat16* __restrict__ Cb, float* __restrict__ Cf,
         int K, int ldc, int nbnLog2,
         const float* __restrict__ biasN, const float* __restrict__ biasM,
         const float* __restrict__ rowsum, const float* __restrict__ prelu_w,
         float* __restrict__ gstats) {
  __shared__ __align__(16) char ldsm[147456];  // 3 x (A 16KB + B 32KB)
  const int tid = threadIdx.x, w = tid >> 6, l = tid & 63;
  const int wm = w >> 2, wn = w & 3;

  // XCD chunk swizzle (grid 256, chunk 32/XCD)
  const int orig = blockIdx.x;
  const int wg = (orig & 7) * 32 + (orig >> 3);
  const int bm = wg >> nbnLog2, bn = wg & ((1 << nbnLog2) - 1);

  const size_t rowB = (size_t)K * 2;
  const char* Ag = (const char*)A + (size_t)bm * 128 * rowB;
  const char* Bg = (const char*)B + (size_t)bn * 256 * rowB;
  const int NT = K >> 6;

  // Stage one 128x64 unit (16 KB, 1024 chunks); 512 thr -> 2 gloads each.
  auto stageU = [&](char* ldsu, const char* srcbase) {
#pragma unroll
    for (int i = 0; i < 2; ++i) {
      const int cb = i * 512 + w * 64;
      const int c = cb + l;
      const int r = c >> 3;
      const int j = (c & 7) ^ (r & 7);
      gload_lds16(srcbase + (size_t)r * rowB + j * 16, ldsu + cb * 16);
    }
  };
  // Stage full K-tile (A + B lo + B hi) = 6 gloads/thread
  auto stT = [&](char* buf, int kt) {
    stageU(buf, Ag + (size_t)kt * 128);
    stageU(buf + 16384, Bg + (size_t)kt * 128);
    stageU(buf + 32768, Bg + (size_t)128 * rowB + (size_t)kt * 128);
  };

  auto rdA = [&](const char* buf, int f, int kk) -> bf16x8 {
    const int R = wm * 64 + f * 16 + (l & 15);
    const int j = kk * 4 + (l >> 4);
    const int chunk = R * 8 + (j ^ (R & 7));
    return *(const bf16x8*)(buf + chunk * 16);
  };
  auto rdB = [&](const char* buf, int nf, int kk) -> bf16x8 {
    const int Rg = wn * 64 + nf * 16 + (l & 15);
    const int hh = Rg >> 7, Rl = Rg & 127;
    const int j = kk * 4 + (l >> 4);
    const int chunk = Rl * 8 + (j ^ (Rl & 7));
    return *(const bf16x8*)(buf + 16384 + hh * 16384 + chunk * 16);
  };

  char* pa = ldsm;
  char* pb = ldsm + 49152;
  char* pc = ldsm + 98304;

  // Prologue: tile0 -> pa, tile1 -> pb (12 loads); drain tile0 (vmcnt(6)).
  stT(pa, 0); stT(pb, 1);
  asm volatile("s_waitcnt vmcnt(6)" ::: "memory");
  BARRIER();

  f32x4 acc[4][4] = {};
  bf16x8 Af[4][2], Bf[4][2];

#pragma unroll 1
  for (int t = 0; t < NT; ++t) {
    const bool s1 = (t + 1 < NT), s2 = (t + 2 < NT);
    // reads of tile t (16 x ds_read_b128)
#pragma unroll
    for (int f = 0; f < 4; ++f)
#pragma unroll
      for (int kk = 0; kk < 2; ++kk) Af[f][kk] = rdA(pa, f, kk);
#pragma unroll
    for (int nf = 0; nf < 4; ++nf)
#pragma unroll
      for (int kk = 0; kk < 2; ++kk) Bf[nf][kk] = rdB(pa, nf, kk);
    // stage tile t+2 into pc (its last reads finished in iter t-1, barrier'd)
    if (s2) stT(pc, t + 2);
    asm volatile("s_waitcnt lgkmcnt(0)" ::: "memory");
    __builtin_amdgcn_sched_barrier(0);
    // 32 MFMA, kk outermost
    __builtin_amdgcn_s_setprio(1);
#pragma unroll
    for (int kk = 0; kk < 2; ++kk)
#pragma unroll
      for (int f = 0; f < 4; ++f)
#pragma unroll
        for (int g = 0; g < 4; ++g)
          acc[f][g] = __builtin_amdgcn_mfma_f32_16x16x32_bf16(Af[f][kk], Bf[g][kk], acc[f][g], 0, 0, 0);
    __builtin_amdgcn_s_setprio(0);
    // gate: tile t+1 resident (drains its 6; leaves t+2's 6 in flight)
    if (s2)      asm volatile("s_waitcnt vmcnt(6)" ::: "memory");
    else if (s1) asm volatile("s_waitcnt vmcnt(0)" ::: "memory");
    BARRIER();
    char* tmp = pa; pa = pb; pb = pc; pc = tmp;
  }

  // Epilogue
  const int r0 = bm * 128 + wm * 64, c0 = bn * 256 + wn * 64;
  float gs = 0.f, gq = 0.f;
#pragma unroll
  for (int mf = 0; mf < 4; ++mf) {
#pragma unroll
    for (int i = 0; i < 4; ++i) {
      const int row = r0 + mf * 16 + ((l >> 4) << 2) + i;
      float rscale = 1.0f;
      if (EPI == 3) rscale = 1.0f / rowsum[row];
#pragma unroll
      for (int nf = 0; nf < 4; ++nf) {
        const int col = c0 + nf * 16 + (l & 15);
        float v = acc[mf][nf][i];
        if (EPI == 0) {
          v += biasN[col];
        } else if (EPI == 1) {
          v += biasM[row];
        } else if (EPI == 3) {
          v = v * rscale + biasN[col];
          v = 0.5f * v * (1.0f + erff(v * 0.70710678118654752f));
        } else if (EPI == 4) {
          v += biasN[col];
          v = (v >= 0.f) ? v : prelu_w[col] * v;
          gs += v; gq += v * v;
        }
        Cb[(size_t)row * ldc + col] = __float2bfloat16(v);
      }
    }
  }
  if (EPI == 4) {
#pragma unroll
    for (int m = 1; m < 64; m <<= 1) {
      gs += __shfl_xor(gs, m);
      gq += __shfl_xor(gq, m);
    }
    if (l == 0) {
      const int g = c0 >> 6;
      atomicAdd(&gstats[g * 2 + 0], gs);
      atomicAdd(&gstats[g * 2 + 1], gq);
    }
  }
}

// ---------------------------------------------------------------- pkern2s
// P = exp(D .* (Q K^T) / 32) + per-row sums.  128x128 tile, BK=64, 256 thr,
// 4 waves (2x2 of 64x64), LDS 64 KB dbuf, 2 blocks/CU (epilogue of one block
// overlaps loop of the other). SUPERTILE XCD swizzle: stile = 8x8 blocks;
// XCD x owns stile-column x -> its 8 K-panels (2 MB) stay L2-resident.
// (R12 measured: FETCH 273 MB, 188 us.)
#define EPAD2 132
__global__ __launch_bounds__(256, 2)
void pkern2s(const __hip_bfloat16* __restrict__ Q, const __hip_bfloat16* __restrict__ Kmat,
             const float* __restrict__ D, __hip_bfloat16* __restrict__ P,
             float* __restrict__ rowsum, int nt) {
  __shared__ __align__(16) char ldsm[65536];  // 2 bufs x (A 16KB + B 16KB); epi 64*132*4=33.8KB
  const int tid = threadIdx.x, w = tid >> 6, l = tid & 63;
  const int wm = w >> 1, wn = w & 1;

  // Supertile swizzle (grid 4096 = 64x64 blocks; stile 8x8; XCD x = stile-col x)
  const int orig = blockIdx.x;
  const int x = orig & 7;          // XCD
  const int i = orig >> 3;         // 0..511 within XCD
  const int sr = i >> 6;           // stile row 0..7
  const int p = i & 63;            // pos in stile
  const int bm = sr * 8 + (p >> 3);
  const int bn = x * 8 + (p & 7);

  const char* Ag = (const char*)Q + (size_t)bm * 128 * 2048;
  const char* Bg = (const char*)Kmat + (size_t)bn * 128 * 2048;

  // Stage one 128-row x 64-col unit (16 KB = 1024 chunks); 256 thr -> 4 gloads.
  auto stageU = [&](int pbuf, int unit, const char* srcbase) {
    char* ldsu = ldsm + pbuf * 32768 + unit * 16384;
#pragma unroll
    for (int q = 0; q < 4; ++q) {
      const int cb = q * 256 + w * 64;
      const int c = cb + l;
      const int r = c >> 3;
      const int j = (c & 7) ^ (r & 7);
      gload_lds16(srcbase + (size_t)r * 2048 + j * 16, ldsu + cb * 16);
    }
  };
  auto stA = [&](int pbuf, int kt) { stageU(pbuf, 0, Ag + (size_t)kt * 128); };
  auto stB = [&](int pbuf, int kt) { stageU(pbuf, 1, Bg + (size_t)kt * 128); };

  auto rdA = [&](int pbuf, int f, int kk) -> bf16x8 {
    const int R = wm * 64 + f * 16 + (l & 15);
    const int j = kk * 4 + (l >> 4);
    const int chunk = R * 8 + (j ^ (R & 7));
    return *(const bf16x8*)(ldsm + pbuf * 32768 + chunk * 16);
  };
  auto rdB = [&](int pbuf, int nf, int kk) -> bf16x8 {
    const int R = wn * 64 + nf * 16 + (l & 15);
    const int j = kk * 4 + (l >> 4);
    const int chunk = R * 8 + (j ^ (R & 7));
    return *(const bf16x8*)(ldsm + pbuf * 32768 + 16384 + chunk * 16);
  };

  // Prologue: buf0 = tile0 (A+B), buf1.A(tile1) in flight.
  stA(0, 0); stB(0, 0);
  stA(1, 1);
  asm volatile("s_waitcnt vmcnt(4)" ::: "memory");
  BARRIER();

  f32x4 acc[4][4] = {};
  bf16x8 Af[4][2], Bf[2][2];

#define PH_A_B01(pbuf)                                         \
  _Pragma("unroll") for (int f = 0; f < 4; ++f)                \
  _Pragma("unroll") for (int kk = 0; kk < 2; ++kk)             \
      Af[f][kk] = rdA(pbuf, f, kk);                            \
  _Pragma("unroll") for (int g = 0; g < 2; ++g)                \
  _Pragma("unroll") for (int kk = 0; kk < 2; ++kk)             \
      Bf[g][kk] = rdB(pbuf, g, kk)

#define PH_B23(pbuf)                                           \
  _Pragma("unroll") for (int g = 0; g < 2; ++g)                \
  _Pragma("unroll") for (int kk = 0; kk < 2; ++kk)             \
      Bf[g][kk] = rdB(pbuf, 2 + g, kk)

#define PRE_MFMA()                                             \
  asm volatile("s_waitcnt lgkmcnt(0)" ::: "memory");           \
  __builtin_amdgcn_sched_barrier(0)

#define MF(CB)                                                          \
  __builtin_amdgcn_s_setprio(1);                                        \
  _Pragma("unroll") for (int kk = 0; kk < 2; ++kk)                      \
  _Pragma("unroll") for (int f = 0; f < 4; ++f)                         \
  _Pragma("unroll") for (int g = 0; g < 2; ++g)                         \
      acc[f][(CB) + g] = __builtin_amdgcn_mfma_f32_16x16x32_bf16(       \
          Af[f][kk], Bf[g][kk], acc[f][(CB) + g], 0, 0, 0);             \
  __builtin_amdgcn_s_setprio(0)

#pragma unroll 1
  for (int t = 0; t < nt; t += 2) {
    const bool s2 = (t + 2 < nt), s3 = (t + 3 < nt);
    // ph1: read buf0 A+B01; stage buf1.B(t+1) (last read prev ph4)
    PH_A_B01(0);
    stB(1, t + 1);
    BARRIER(); PRE_MFMA();
    MF(0);
    BARRIER();
    // ph2: read buf0.B23; stage buf0.A(t+2); gate: t+1 A+B complete
    PH_B23(0);
    if (s2) stA(0, t + 2);
    if (s2) asm volatile("s_waitcnt vmcnt(4)" ::: "memory");
    else    asm volatile("s_waitcnt vmcnt(0)" ::: "memory");
    BARRIER(); PRE_MFMA();
    MF(2);
    BARRIER();
    // ph3: read buf1 A+B01; stage buf0.B(t+2)
    PH_A_B01(1);
    if (s2) stB(0, t + 2);
    BARRIER(); PRE_MFMA();
    MF(0);
    BARRIER();
    // ph4: read buf1.B23; stage buf1.A(t+3); gate: t+2 A+B complete
    PH_B23(1);
    if (s3) stA(1, t + 3);
    if (s3)      asm volatile("s_waitcnt vmcnt(4)" ::: "memory");
    else if (s2) asm volatile("s_waitcnt vmcnt(0)" ::: "memory");
    else         asm volatile("s_waitcnt vmcnt(0)" ::: "memory");
    BARRIER(); PRE_MFMA();
    MF(2);
    BARRIER();
  }
#undef PH_A_B01
#undef PH_B23
#undef PRE_MFMA
#undef MF

  // ---- Epilogue: LDS transpose in 64-row halves + T14 D-prefetch ----
  float* lds32 = (float*)ldsm;
  const int rbase = bm * 128, cbase = bn * 128;
  const int rth = tid >> 3;            // 0..31 row within 32-row chunk
  const int cl = (tid & 7) * 16;       // 0..112
#pragma unroll 1
  for (int h = 0; h < 2; ++h) {
    // (1) prefetch this half's D (rows h*64 + it*32 + rth), 8 float4 = 32 VGPR
    float4 dreg[8];
#pragma unroll
    for (int it = 0; it < 2; ++it) {
      const size_t gof = (size_t)(rbase + h * 64 + it * 32 + rth) * 8192 + (cbase + cl);
#pragma unroll
      for (int q = 0; q < 4; ++q) dreg[it * 4 + q] = *(const float4*)(D + gof + q * 4);
    }
    // (2) dump half h's acc (waves wm==h) into LDS [64][EPAD2]
    BARRIER();
    if (wm == h) {
#pragma unroll
      for (int mf = 0; mf < 4; ++mf)
#pragma unroll
        for (int nf = 0; nf < 4; ++nf)
#pragma unroll
          for (int i2 = 0; i2 < 4; ++i2)
            lds32[(mf * 16 + ((l >> 4) << 2) + i2) * EPAD2 + (wn * 64 + nf * 16 + (l & 15))] =
                acc[mf][nf][i2];
    }
    asm volatile("s_waitcnt lgkmcnt(0)" ::: "memory");
    BARRIER();
    // (3) consume: 2 iters x 32 rows; 8 thr/row x 16 f32
#pragma unroll
    for (int it = 0; it < 2; ++it) {
      const int rl = it * 32 + rth;
      const int row = rbase + h * 64 + rl;
      const size_t gof = (size_t)row * 8192 + (cbase + cl);
      float pv[16];
#pragma unroll
      for (int q = 0; q < 4; ++q) {
        const float4 s = *(const float4*)(lds32 + rl * EPAD2 + cl + q * 4);
        const float4 d = dreg[it * 4 + q];
        pv[q * 4 + 0] = __expf(d.x * (s.x * 0.03125f));
        pv[q * 4 + 1] = __expf(d.y * (s.y * 0.03125f));
        pv[q * 4 + 2] = __expf(d.z * (s.z * 0.03125f));
        pv[q * 4 + 3] = __expf(d.w * (s.w * 0.03125f));
      }
      ushort8 o0, o1;
#pragma unroll
      for (int q = 0; q < 8; ++q) { o0[q] = f2bu(pv[q]); o1[q] = f2bu(pv[8 + q]); }
      *(ushort8*)((ushort_t*)P + gof) = o0;
      *(ushort8*)((ushort_t*)P + gof + 8) = o1;
      float rs = 0.f;
#pragma unroll
      for (int q = 0; q < 16; ++q) rs += pv[q];
      rs += __shfl_xor(rs, 1); rs += __shfl_xor(rs, 2); rs += __shfl_xor(rs, 4);
      if ((tid & 7) == 0) atomicAdd(&rowsum[row], rs);
    }
  }
}
#undef EPAD2

// ---------------------------------------------------------------- GroupNorm finalize (bf16 x)

__global__ void gn_finalize(const __hip_bfloat16* __restrict__ x, const float* __restrict__ gstats,
                            const float* __restrict__ gw, const float* __restrict__ gb,
                            float* __restrict__ out, int n) {
  __shared__ float sm[16], sr[16];
  if (threadIdx.x < 16) {
    const float cnt = 64.0f * 8192.0f;
    const float s = gstats[threadIdx.x * 2 + 0];
    const float q = gstats[threadIdx.x * 2 + 1];
    const float mean = s / cnt;
    const float var = q / cnt - mean * mean;
    sm[threadIdx.x] = mean;
    sr[threadIdx.x] = rsqrtf(var + 1e-5f);
  }
  __syncthreads();
  const int i8 = (blockIdx.x * 256 + threadIdx.x) * 8;
  if (i8 >= n) return;
  const ushort8 v = *(const ushort8*)((const ushort_t*)x + i8);
  const int c = i8 & 1023;     // 8 consecutive channels, same 64-channel group
  const int g = c >> 6;
  const float mean = sm[g], r = sr[g];
  float4 o0, o1;
  o0.x = (bu2f(v[0]) - mean) * r * gw[c + 0] + gb[c + 0];
  o0.y = (bu2f(v[1]) - mean) * r * gw[c + 1] + gb[c + 1];
  o0.z = (bu2f(v[2]) - mean) * r * gw[c + 2] + gb[c + 2];
  o0.w = (bu2f(v[3]) - mean) * r * gw[c + 3] + gb[c + 3];
  o1.x = (bu2f(v[4]) - mean) * r * gw[c + 4] + gb[c + 4];
  o1.y = (bu2f(v[5]) - mean) * r * gw[c + 5] + gb[c + 5];
  o1.z = (bu2f(v[6]) - mean) * r * gw[c + 6] + gb[c + 6];
  o1.w = (bu2f(v[7]) - mean) * r * gw[c + 7] + gb[c + 7];
  *(float4*)(out + i8) = o0;
  *(float4*)(out + i8 + 4) = o1;
}

// ---------------------------------------------------------------- launch

extern "C" void kernel_launch(void* const* d_in, const int* in_sizes, int n_in,
                              void* d_out, int out_size, void* d_ws, size_t ws_size,
                              hipStream_t stream) {
  const float* h  = (const float*)d_in[0];
  const float* D  = (const float*)d_in[1];
  const float* hp = (const float*)d_in[2];
  const float* Wq = (const float*)d_in[3];
  const float* bq = (const float*)d_in[4];
  const float* Wk = (const float*)d_in[5];
  const float* bk = (const float*)d_in[6];
  const float* Wv = (const float*)d_in[7];
  const float* bv = (const float*)d_in[8];
  const float* Wr = (const float*)d_in[9];
  const float* br = (const float*)d_in[10];
  const float* Wc = (const float*)d_in[11];
  const float* bc = (const float*)d_in[12];
  const float* Wp = (const float*)d_in[13];
  const float* bp = (const float*)d_in[14];
  const float* pw = (const float*)d_in[15];
  const float* gw = (const float*)d_in[16];
  const float* gb = (const float*)d_in[17];
  float* out = (float*)d_out;

  char* ws = (char*)d_ws;
  size_t off = 0;
  auto alloc = [&](size_t b) {
    char* p = ws + off;
    off += (b + 255) & ~(size_t)255;
    return p;
  };
  __hip_bfloat16* hb   = (__hip_bfloat16*)alloc(8192ull * 1024 * 2);
  __hip_bfloat16* hpb  = (__hip_bfloat16*)alloc(8192ull * 1024 * 2);
  __hip_bfloat16* Wqb  = (__hip_bfloat16*)alloc(1024ull * 1024 * 2);
  __hip_bfloat16* Wkb  = (__hip_bfloat16*)alloc(1024ull * 1024 * 2);
  __hip_bfloat16* Wvb  = (__hip_bfloat16*)alloc(1024ull * 1024 * 2);
  __hip_bfloat16* Wrb  = (__hip_bfloat16*)alloc(1024ull * 1024 * 2);
  __hip_bfloat16* Wcb  = (__hip_bfloat16*)alloc(1024ull * 1024 * 2);
  __hip_bfloat16* Wpb  = (__hip_bfloat16*)alloc(1024ull * 2048 * 2);
  __hip_bfloat16* Qb   = (__hip_bfloat16*)alloc(8192ull * 1024 * 2);
  __hip_bfloat16* Kb   = (__hip_bfloat16*)alloc(8192ull * 1024 * 2);
  __hip_bfloat16* Vt   = (__hip_bfloat16*)alloc(1024ull * 8192 * 2);
  __hip_bfloat16* R0   = (__hip_bfloat16*)alloc(8192ull * 1024 * 2);
  __hip_bfloat16* comb = (__hip_bfloat16*)alloc(8192ull * 2048 * 2);
  __hip_bfloat16* P    = (__hip_bfloat16*)alloc(8192ull * 8192 * 2);
  __hip_bfloat16* xbufb = (__hip_bfloat16*)alloc(8192ull * 1024 * 2);
  float* rowsum = (float*)alloc(8192ull * 4);
  float* gstats = (float*)alloc(128);
  if (off > ws_size) return;

  hipMemsetAsync(rowsum, 0, 8192 * 4, stream);
  hipMemsetAsync(gstats, 0, 128, stream);

  // All conversions in one launch. Segments (blocks of 1024 elems):
  CvtArgs ca;
  ca.src[0] = h;  ca.dst[0] = hb;  ca.base[0] = 0;
  ca.src[1] = hp; ca.dst[1] = hpb; ca.base[1] = 8192;
  ca.src[2] = Wq; ca.dst[2] = Wqb; ca.base[2] = 16384;
  ca.src[3] = Wk; ca.dst[3] = Wkb; ca.base[3] = 17408;
  ca.src[4] = Wv; ca.dst[4] = Wvb; ca.base[4] = 18432;
  ca.src[5] = Wr; ca.dst[5] = Wrb; ca.base[5] = 19456;
  ca.src[6] = Wc; ca.dst[6] = Wcb; ca.base[6] = 20480;
  ca.src[7] = Wp; ca.dst[7] = Wpb; ca.base[7] = 21504;
  f2b_all<<<dim3(23552), 256, 0, stream>>>(ca);

  // Q = h Wq^T + bq ; K = h Wk^T + bk     [8192,1024]
  g1p<0><<<dim3(256), 512, 0, stream>>>(hb, Wqb, Qb, nullptr, 1024, 1024, 2, bq, nullptr, nullptr, nullptr, nullptr);
  g1p<0><<<dim3(256), 512, 0, stream>>>(hb, Wkb, Kb, nullptr, 1024, 1024, 2, bk, nullptr, nullptr, nullptr, nullptr);
  // Vt = Wv h^T + bv(per row)             [1024,8192]
  g1p<1><<<dim3(256), 512, 0, stream>>>(Wvb, hb, Vt, nullptr, 1024, 8192, 5, nullptr, bv, nullptr, nullptr, nullptr);
  // P = exp(D .* QK^T/32), rowsum         [8192,8192]  (supertile 2-blk/CU engine)
  pkern2s<<<dim3(4096), 256, 0, stream>>>(Qb, Kb, D, P, rowsum, 16);
  // R0 = P V (= P Vt^T)                   [8192,1024]
  g1p<2><<<dim3(256), 512, 0, stream>>>(P, Vt, R0, nullptr, 8192, 1024, 2, nullptr, nullptr, nullptr, nullptr, nullptr);
  // comb[:, :1024] = gelu((R0 Wr^T)/rowsum + br)
  g1p<3><<<dim3(256), 512, 0, stream>>>(R0, Wrb, comb, nullptr, 1024, 2048, 2, br, nullptr, rowsum, nullptr, nullptr);
  // comb[:, 1024:] = hp Wc^T + bc
  g1p<0><<<dim3(256), 512, 0, stream>>>(hpb, Wcb, comb + 1024, nullptr, 1024, 2048, 2, bc, nullptr, nullptr, nullptr, nullptr);
  // x = prelu(comb Wp^T + bp) -> bf16, group stats
  g1p<4><<<dim3(256), 512, 0, stream>>>(comb, Wpb, xbufb, nullptr, 2048, 1024, 2, bp, nullptr, nullptr, pw, gstats);
  // groupnorm
  gn_finalize<<<dim3(4096), 256, 0, stream>>>(xbufb, gstats, gw, gb, out, 8192 * 1024);
}